// Round 8
// baseline (471.779 us; speedup 1.0000x reference)
//
#include <hip/hip_runtime.h>
#include <hip/hip_bf16.h>
#include <stdint.h>

// Problem constants
#define T_SEQ 2048
#define DM    2048
#define NH    16
#define NKVH  4
#define HD    128
#define NBATCH 4
#define BT    (NBATCH * T_SEQ)   // 8192 rows of x
#define ATT_SCALE 0.08838834764831845f  // 1/sqrt(128)
#define LOG2E 1.4426950408889634f

typedef __attribute__((ext_vector_type(8))) short bf16x8;
typedef __attribute__((ext_vector_type(4))) float f32x4;
typedef __attribute__((ext_vector_type(16))) float f32x16;
typedef __attribute__((ext_vector_type(8))) unsigned short ushort8;
typedef __attribute__((ext_vector_type(4))) unsigned short ushort4v;

static __device__ __forceinline__ unsigned short f2bf(float f) {
  __hip_bfloat16 h = __float2bfloat16(f);
  return __builtin_bit_cast(unsigned short, h);
}
static __device__ __forceinline__ float bf2f(unsigned short u) {
  unsigned int v = ((unsigned int)u) << 16;
  return __builtin_bit_cast(float, v);
}
static __device__ __forceinline__ unsigned int packbf2(float a, float b) {
  return (unsigned int)f2bf(a) | ((unsigned int)f2bf(b) << 16);
}

#define GLDS16(g, l)                                                        \
  __builtin_amdgcn_global_load_lds(                                         \
      (const __attribute__((address_space(1))) void*)(g),                   \
      (__attribute__((address_space(3))) void*)(l), 16, 0, 0)

// ---------------------------------------------------------------- cast x
__global__ __launch_bounds__(256) void castx_k(const float* __restrict__ x,
                                               unsigned short* __restrict__ xb) {
  int i = (blockIdx.x * 256 + threadIdx.x) * 4;
  float4 v = *(const float4*)&x[i];
  ushort4v o;
  o[0] = f2bf(v.x); o[1] = f2bf(v.y); o[2] = f2bf(v.z); o[3] = f2bf(v.w);
  *(ushort4v*)&xb[i] = o;
}

// ------------------------------------------- cast + transpose weight (K=2048 rows)
__global__ __launch_bounds__(256) void transw_k(const float* __restrict__ src,
                                                unsigned short* __restrict__ dst,
                                                int ncols) {
  __shared__ unsigned short t[64][72];
  int n0 = blockIdx.x * 64, r0 = blockIdx.y * 64;
  int tid = threadIdx.x;
  int tx = tid & 15, ty = tid >> 4;
#pragma unroll
  for (int i = 0; i < 4; i++) {
    int r = ty * 4 + i;
    float4 v = *(const float4*)&src[(size_t)(r0 + r) * ncols + n0 + tx * 4];
    t[r][tx * 4 + 0] = f2bf(v.x);
    t[r][tx * 4 + 1] = f2bf(v.y);
    t[r][tx * 4 + 2] = f2bf(v.z);
    t[r][tx * 4 + 3] = f2bf(v.w);
  }
  __syncthreads();
  int nl = tid >> 2, seg = tid & 3;
  ushort8 o0, o1;
#pragma unroll
  for (int j = 0; j < 8; j++) {
    o0[j] = t[seg * 16 + j][nl];
    o1[j] = t[seg * 16 + 8 + j][nl];
  }
  size_t base = (size_t)(n0 + nl) * 2048 + r0 + seg * 16;
  *(ushort8*)&dst[base] = o0;
  *(ushort8*)&dst[base + 8] = o1;
}

// ---------------------------------------------------------------- GEMM (ring-pipelined)
// BM=128 x BN=256 x BK=32; 512 threads = 8 waves (2x4); per-wave 64x64 out.
// 3-slot LDS ring (72 KB), staged via global_load_lds; one raw s_barrier +
// counted vmcnt(3) per K-tile (vmcnt(0) only on the final tile) so staging
// overlaps compute. BK=32 (64B rows) makes fragment ds_read_b128 inherently
// bank-balanced -> linear LDS, linear gload source (no swizzle needed).
// EPI 0: route to Q / K / V^T.  EPI 1: fp32 out.
template <int EPI>
__global__ __launch_bounds__(512) void gemm2_k(const unsigned short* __restrict__ A,
                                               const unsigned short* __restrict__ Bt,
                                               unsigned short* __restrict__ q_out,
                                               unsigned short* __restrict__ k_out,
                                               unsigned short* __restrict__ v_out,
                                               float* __restrict__ f_out) {
  // slot: A [128][32] @ 0 (4096 ushorts), B [256][32] @ 4096 (8192 ushorts)
  __shared__ __align__(16) unsigned short smem[3 * 12288];

  const int tid = threadIdx.x;
  const int lane = tid & 63, wid = tid >> 6;
  const int wm = wid >> 2, wn = wid & 3;           // 2 x 4 wave grid
  const int lr = lane & 15, lk = (lane >> 4) * 8;

  // XCD-chunked block swizzle (grid is a multiple of 8)
  const int nwg = gridDim.x;
  const int cpx = nwg >> 3;
  const int swz = (blockIdx.x & 7) * cpx + (blockIdx.x >> 3);
  const int bx = swz & 63;                         // 64 M-tiles (8192/128)
  const int by = swz >> 6;
  const int row0 = bx * 128, n00 = by * 256;

  // staging: A 8KB (1 gload/thread), B 16KB (2 gloads/thread); linear
  const unsigned short* Aptr = A + (size_t)(row0 + (tid >> 2)) * 2048 + (tid & 3) * 8;
  const unsigned short* Bptr = Bt + (size_t)(n00 + (tid >> 2)) * 2048 + (tid & 3) * 8;

  f32x4 acc[4][4] = {};

  // prologue: stage K-tiles 0,1
#pragma unroll
  for (int p = 0; p < 2; p++) {
    unsigned short* s = &smem[p * 12288];
    GLDS16(Aptr + p * 32, &s[tid * 8]);
    GLDS16(Bptr + p * 32, &s[4096 + tid * 8]);
    GLDS16(Bptr + (size_t)128 * 2048 + p * 32, &s[8192 + tid * 8]);
  }

#pragma unroll 1
  for (int i = 0; i < 64; ++i) {
    if (i == 63) {
      asm volatile("s_waitcnt vmcnt(0)" ::: "memory");
    } else {
      asm volatile("s_waitcnt vmcnt(3)" ::: "memory");
    }
    asm volatile("s_barrier" ::: "memory");
    if (i + 2 < 64) {
      const int k0 = (i + 2) * 32;
      unsigned short* s = &smem[((i + 2) % 3) * 12288];
      GLDS16(Aptr + k0, &s[tid * 8]);
      GLDS16(Bptr + k0, &s[4096 + tid * 8]);
      GLDS16(Bptr + (size_t)128 * 2048 + k0, &s[8192 + tid * 8]);
    }

    const unsigned short* sA = &smem[(i % 3) * 12288];
    const unsigned short* sB = sA + 4096;
    bf16x8 af[4], bfr[4];
#pragma unroll
    for (int mi = 0; mi < 4; mi++)
      af[mi] = *(const bf16x8*)&sA[(wm * 64 + mi * 16 + lr) * 32 + lk];
#pragma unroll
    for (int ni = 0; ni < 4; ni++)
      bfr[ni] = *(const bf16x8*)&sB[(wn * 64 + ni * 16 + lr) * 32 + lk];

    __builtin_amdgcn_s_setprio(1);
#pragma unroll
    for (int mi = 0; mi < 4; mi++)
#pragma unroll
      for (int ni = 0; ni < 4; ni++)
        acc[mi][ni] =
            __builtin_amdgcn_mfma_f32_16x16x32_bf16(af[mi], bfr[ni], acc[mi][ni], 0, 0, 0);
    __builtin_amdgcn_s_setprio(0);
  }

  const int rbase = row0 + wm * 64;
  const int cbase = n00 + wn * 64;
#pragma unroll
  for (int mi = 0; mi < 4; mi++)
#pragma unroll
    for (int ni = 0; ni < 4; ni++)
#pragma unroll
      for (int r = 0; r < 4; r++) {
        int row = rbase + mi * 16 + (lane >> 4) * 4 + r;
        int col = cbase + ni * 16 + lr;
        float v = acc[mi][ni][r];
        if (EPI == 0) {
          if (col < 2048) {
            q_out[(size_t)row * 2048 + col] = f2bf(v);
          } else if (col < 2560) {
            k_out[(size_t)row * 512 + (col - 2048)] = f2bf(v);
          } else {
            int nv = col - 2560;
            int kvh = nv >> 7, d = nv & 127;
            int b = row >> 11, tt = row & 2047;
            v_out[((size_t)(b * NKVH + kvh) * HD + d) * T_SEQ + tt] = f2bf(v);
          }
        } else {
          f_out[(size_t)row * 2048 + col] = v;
        }
      }
}

// ---------------------------------------------------------------- RoPE tables + apply
__global__ __launch_bounds__(256) void rope_tab_k(float2* __restrict__ tab) {
  int idx = blockIdx.x * 256 + threadIdx.x;   // 2048*64 entries
  int t = idx >> 6, i = idx & 63;
  float theta = exp2f(-(float)i * (13.287712379549449f / 64.0f));
  float s, c;
  sincosf((float)t * theta, &s, &c);
  tab[idx] = make_float2(c, s);
}

__global__ __launch_bounds__(256) void rope_k(unsigned short* __restrict__ qb,
                                              unsigned short* __restrict__ kb,
                                              const float2* __restrict__ tab) {
  int idx = blockIdx.x * 256 + threadIdx.x;
  int i = idx & 63;
  int wi = idx >> 6;
  int hh = wi % (NH + NKVH);
  int bt = wi / (NH + NKVH);
  int t = bt & (T_SEQ - 1);
  unsigned short* p = (hh < NH) ? (qb + (size_t)bt * 2048 + hh * HD)
                                : (kb + (size_t)bt * 512 + (hh - NH) * HD);
  float2 cs = tab[(t << 6) + i];
  float x1 = bf2f(p[i]), x2 = bf2f(p[i + 64]);
  p[i] = f2bf(x1 * cs.x - x2 * cs.y);
  p[i + 64] = f2bf(x1 * cs.y + x2 * cs.x);
}

// ---------------------------------------------------------------- flash attention
// (unchanged from round 7 — 3-slot ring, counted vmcnt, reverse-K, defer-rescale)
__global__ __launch_bounds__(256) void attn_k(const unsigned short* __restrict__ qb,
                                              const unsigned short* __restrict__ kb,
                                              const unsigned short* __restrict__ vt,
                                              unsigned short* __restrict__ ao) {
  __shared__ __align__(16) unsigned short smem[24576];

  const int bid = blockIdx.x;
  const int j = 15 - (bid >> 6);                 // q-tile, heavy first
  const int g = (bid & 7) | (((bid >> 3) & 1) << 3);  // (b,kvh) group -> XCD bid&7
  const int hh = (bid >> 4) & 3;
  const int b = g >> 2, kvh = g & 3;
  const int h = kvh * 4 + hh;

  const int tid = threadIdx.x;
  const int wid = tid >> 6, lane = tid & 63;
  const int l31 = lane & 31, lh = lane >> 5;
  const int xr = l31 & 7;
  const float slope2 = exp2f(-0.5f * (float)(h + 1)) * LOG2E;
  const float scale2 = ATT_SCALE * LOG2E;

  const int q0 = j * 128 + wid * 32;
  const int dt_w = j * 4 + wid;
  const int nt = j * 4 + 4;

  const int krow = tid >> 4;
  const int cgk = (tid & 15) ^ (krow & 7);
  const int vr = tid >> 3;
  const int cgv = (tid & 7) ^ (vr & 7);

  const unsigned short* khead = kb + (size_t)(b * T_SEQ) * 512 + kvh * 128;
  const unsigned short* vhead = vt + (size_t)(b * NKVH + kvh) * HD * T_SEQ;

  auto stage = [&](int slot, int tile) {
    const int k0 = tile * 32;
    unsigned short* base = &smem[slot * 8192];
    GLDS16(khead + (size_t)(k0 + krow) * 512 + cgk * 8, base + tid * 8);
    GLDS16(khead + (size_t)(k0 + 16 + krow) * 512 + cgk * 8, base + 2048 + tid * 8);
    GLDS16(vhead + (size_t)(((cgv >> 2) << 6) + vr) * T_SEQ + k0 + (cgv & 3) * 8,
           base + 4096 + tid * 8);
    GLDS16(vhead + (size_t)(((cgv >> 2) << 6) + 32 + vr) * T_SEQ + k0 + (cgv & 3) * 8,
           base + 6144 + tid * 8);
  };

  unsigned short (*ot)[32][136] = (unsigned short(*)[32][136])smem;

  const unsigned short* qrow =
      qb + ((size_t)(b * T_SEQ + q0 + l31)) * 2048 + h * HD + lh * 8;
  bf16x8 qf[8];
#pragma unroll
  for (int ds = 0; ds < 8; ds++) qf[ds] = *(const bf16x8*)&qrow[ds * 16];

  f32x16 oacc[4] = {};
  float m2 = -1e30f, l_half = 0.f;
  const float arow = -slope2 * (float)(q0 + l31);

  stage(0, nt - 1);
  stage(1, nt - 2);

#pragma unroll 1
  for (int it = 0; it < nt; ++it) {
    const int tt = nt - 1 - it;
    if (it == nt - 1) {
      asm volatile("s_waitcnt vmcnt(0)" ::: "memory");
    } else {
      asm volatile("s_waitcnt vmcnt(4)" ::: "memory");
    }
    asm volatile("s_barrier" ::: "memory");
    if (tt >= 2) stage((it + 2) % 3, tt - 2);

    if (tt <= dt_w) {
      const int slot = it % 3;
      const unsigned short* Kb = &smem[slot * 8192];
      const unsigned short* Vb = &smem[slot * 8192 + 4096];
      const int k0 = tt * 32;

      bf16x8 kf[8];
#pragma unroll
      for (int ds = 0; ds < 8; ds++)
        kf[ds] = *(const bf16x8*)&Kb[l31 * 128 + ((2 * ds + lh) ^ xr) * 8];

      __builtin_amdgcn_s_setprio(1);
      f32x16 sc = 0.f;
#pragma unroll
      for (int ds = 0; ds < 8; ds++)
        sc = __builtin_amdgcn_mfma_f32_32x32x16_bf16(kf[ds], qf[ds], sc, 0, 0, 0);
      __builtin_amdgcn_s_setprio(0);

      bf16x8 vf[4][2];
#pragma unroll
      for (int dt = 0; dt < 4; dt++)
#pragma unroll
        for (int ks = 0; ks < 2; ks++)
          vf[dt][ks] = *(const bf16x8*)&Vb[((dt & 1) * 32 + l31) * 64 +
                                           (((dt >> 1) * 4 + 2 * ks + lh) ^ xr) * 8];

      float s[16];
      const float ab = fmaf(slope2, (float)k0, arow);
      const bool diag = (tt == dt_w);
#pragma unroll
      for (int r = 0; r < 16; r++) {
        const int crow = (r & 3) + 8 * (r >> 2) + 4 * lh;
        float v = fmaf(sc[r], scale2, fmaf(slope2, (float)crow, ab));
        if (diag && crow > l31) v = -1e30f;
        s[r] = v;
      }

      float t8[8], t4[4];
#pragma unroll
      for (int i = 0; i < 8; i++) t8[i] = fmaxf(s[i], s[i + 8]);
#pragma unroll
      for (int i = 0; i < 4; i++) t4[i] = fmaxf(t8[i], t8[i + 4]);
      float mx = fmaxf(fmaxf(t4[0], t4[1]), fmaxf(t4[2], t4[3]));

      float pr[16];
#pragma unroll
      for (int r = 0; r < 16; r++) pr[r] = exp2f(s[r] - m2);

      mx = fmaxf(mx, __shfl_xor(mx, 32));
      if (__any(mx > m2 + 8.f)) {
        const float mnew = fmaxf(m2, mx);
        const float corr = exp2f(m2 - mnew);
        l_half *= corr;
#pragma unroll
        for (int dt = 0; dt < 4; dt++) oacc[dt] *= corr;
#pragma unroll
        for (int r = 0; r < 16; r++) pr[r] = exp2f(s[r] - mnew);
        m2 = mnew;
      }

      float a8[8], a4[4];
#pragma unroll
      for (int i = 0; i < 8; i++) a8[i] = pr[i] + pr[i + 8];
#pragma unroll
      for (int i = 0; i < 4; i++) a4[i] = a8[i] + a8[i + 4];
      l_half += (a4[0] + a4[1]) + (a4[2] + a4[3]);

      unsigned int w[8];
#pragma unroll
      for (int i = 0; i < 8; i++) w[i] = packbf2(pr[2 * i], pr[2 * i + 1]);
      const unsigned int ta = __shfl_xor(lh ? w[0] : w[2], 32);
      const unsigned int tb = __shfl_xor(lh ? w[1] : w[3], 32);
      const unsigned int tc = __shfl_xor(lh ? w[4] : w[6], 32);
      const unsigned int td = __shfl_xor(lh ? w[5] : w[7], 32);
      union U4 { unsigned int u[4]; bf16x8 v; } f0, f1;
      f0.u[0] = lh ? ta : w[0];
      f0.u[1] = lh ? tb : w[1];
      f0.u[2] = lh ? w[2] : ta;
      f0.u[3] = lh ? w[3] : tb;
      f1.u[0] = lh ? tc : w[4];
      f1.u[1] = lh ? td : w[5];
      f1.u[2] = lh ? w[6] : tc;
      f1.u[3] = lh ? w[7] : td;

      __builtin_amdgcn_s_setprio(1);
#pragma unroll
      for (int dt = 0; dt < 4; dt++) {
        oacc[dt] =
            __builtin_amdgcn_mfma_f32_32x32x16_bf16(vf[dt][0], f0.v, oacc[dt], 0, 0, 0);
        oacc[dt] =
            __builtin_amdgcn_mfma_f32_32x32x16_bf16(vf[dt][1], f1.v, oacc[dt], 0, 0, 0);
      }
      __builtin_amdgcn_s_setprio(0);
    }
  }

  const float l_tot = l_half + __shfl_xor(l_half, 32);
  const float inv = 1.0f / l_tot;
  __syncthreads();
#pragma unroll
  for (int dt = 0; dt < 4; dt++)
#pragma unroll
    for (int rg = 0; rg < 4; rg++) {
      ushort4v o;
#pragma unroll
      for (int jj = 0; jj < 4; jj++) o[jj] = f2bf(oacc[dt][rg * 4 + jj] * inv);
      *(ushort4v*)&ot[wid][l31][dt * 32 + rg * 8 + lh * 4] = o;
    }
  __syncthreads();
  const int rrow = lane >> 4, chunk = lane & 15;
#pragma unroll
  for (int ps = 0; ps < 8; ps++) {
    const int row = ps * 4 + rrow;
    ushort8 v = *(const ushort8*)&ot[wid][row][chunk * 8];
    *(ushort8*)&ao[((size_t)(b * T_SEQ + q0 + row)) * 2048 + h * HD + chunk * 8] = v;
  }
}

// ---------------------------------------------------------------- launch
extern "C" void kernel_launch(void* const* d_in, const int* in_sizes, int n_in,
                              void* d_out, int out_size, void* d_ws, size_t ws_size,
                              hipStream_t stream) {
  const float* x = (const float*)d_in[0];
  const float* Wq = (const float*)d_in[1];
  const float* Wk = (const float*)d_in[2];
  const float* Wv = (const float*)d_in[3];
  const float* Wo = (const float*)d_in[4];

  char* w = (char*)d_ws;
  unsigned short* xb = (unsigned short*)w;                       // 33.5MB; rope table + attn out reuse
  unsigned short* wqt = (unsigned short*)(w + 33554432);         // 12.6MB; reused for Wo^T
  unsigned short* qb = (unsigned short*)(w + 33554432 + 12582912);
  unsigned short* kb = (unsigned short*)(w + 33554432 + 12582912 + 33554432);
  unsigned short* vtb = (unsigned short*)(w + 33554432 + 12582912 + 33554432 + 8388608);
  float2* rtab = (float2*)w;  // 1MB, lives in xb region between gemm0 and attn

  castx_k<<<16384, 256, 0, stream>>>(x, xb);
  transw_k<<<dim3(32, 32), 256, 0, stream>>>(Wq, wqt, 2048);
  transw_k<<<dim3(8, 32), 256, 0, stream>>>(Wk, wqt + (size_t)2048 * 2048, 512);
  transw_k<<<dim3(8, 32), 256, 0, stream>>>(Wv, wqt + (size_t)2560 * 2048, 512);
  gemm2_k<0><<<768, 512, 0, stream>>>(xb, wqt, qb, kb, vtb, nullptr);
  // xb free until attn output: build rope table there
  rope_tab_k<<<512, 256, 0, stream>>>(rtab);
  rope_k<<<40960, 256, 0, stream>>>(qb, kb, rtab);
  transw_k<<<dim3(32, 32), 256, 0, stream>>>(Wo, wqt, 2048);
  attn_k<<<1024, 256, 0, stream>>>(qb, kb, vtb, xb);
  gemm2_k<1><<<512, 512, 0, stream>>>(xb, wqt, nullptr, nullptr, nullptr,
                                      (float*)d_out);
}

// Round 9
// 465.976 us; speedup vs baseline: 1.0125x; 1.0125x over previous
//
#include <hip/hip_runtime.h>
#include <hip/hip_bf16.h>
#include <stdint.h>

// Problem constants
#define T_SEQ 2048
#define DM    2048
#define NH    16
#define NKVH  4
#define HD    128
#define NBATCH 4
#define BT    (NBATCH * T_SEQ)   // 8192 rows of x
#define ATT_SCALE 0.08838834764831845f  // 1/sqrt(128)
#define LOG2E 1.4426950408889634f

typedef __attribute__((ext_vector_type(8))) short bf16x8;
typedef __attribute__((ext_vector_type(4))) float f32x4;
typedef __attribute__((ext_vector_type(16))) float f32x16;
typedef __attribute__((ext_vector_type(8))) unsigned short ushort8;
typedef __attribute__((ext_vector_type(4))) unsigned short ushort4v;

static __device__ __forceinline__ unsigned short f2bf(float f) {
  __hip_bfloat16 h = __float2bfloat16(f);
  return __builtin_bit_cast(unsigned short, h);
}
static __device__ __forceinline__ float bf2f(unsigned short u) {
  unsigned int v = ((unsigned int)u) << 16;
  return __builtin_bit_cast(float, v);
}
// HW packed f32->bf16 pair (RNE): lo=a, hi=b. T12 recipe (no builtin on gfx950).
static __device__ __forceinline__ unsigned int cvtpk(float a, float b) {
  unsigned int r;
  asm("v_cvt_pk_bf16_f32 %0, %1, %2" : "=v"(r) : "v"(a), "v"(b));
  return r;
}

#define GLDS16(g, l)                                                        \
  __builtin_amdgcn_global_load_lds(                                         \
      (const __attribute__((address_space(1))) void*)(g),                   \
      (__attribute__((address_space(3))) void*)(l), 16, 0, 0)

// ---------------------------------------------------------------- cast x
__global__ __launch_bounds__(256) void castx_k(const float* __restrict__ x,
                                               unsigned short* __restrict__ xb) {
  int i = (blockIdx.x * 256 + threadIdx.x) * 4;
  float4 v = *(const float4*)&x[i];
  ushort4v o;
  o[0] = f2bf(v.x); o[1] = f2bf(v.y); o[2] = f2bf(v.z); o[3] = f2bf(v.w);
  *(ushort4v*)&xb[i] = o;
}

// ------------------------------------------- cast + transpose weight (K=2048 rows)
__global__ __launch_bounds__(256) void transw_k(const float* __restrict__ src,
                                                unsigned short* __restrict__ dst,
                                                int ncols) {
  __shared__ unsigned short t[64][72];
  int n0 = blockIdx.x * 64, r0 = blockIdx.y * 64;
  int tid = threadIdx.x;
  int tx = tid & 15, ty = tid >> 4;
#pragma unroll
  for (int i = 0; i < 4; i++) {
    int r = ty * 4 + i;
    float4 v = *(const float4*)&src[(size_t)(r0 + r) * ncols + n0 + tx * 4];
    t[r][tx * 4 + 0] = f2bf(v.x);
    t[r][tx * 4 + 1] = f2bf(v.y);
    t[r][tx * 4 + 2] = f2bf(v.z);
    t[r][tx * 4 + 3] = f2bf(v.w);
  }
  __syncthreads();
  int nl = tid >> 2, seg = tid & 3;
  ushort8 o0, o1;
#pragma unroll
  for (int j = 0; j < 8; j++) {
    o0[j] = t[seg * 16 + j][nl];
    o1[j] = t[seg * 16 + 8 + j][nl];
  }
  size_t base = (size_t)(n0 + nl) * 2048 + r0 + seg * 16;
  *(ushort8*)&dst[base] = o0;
  *(ushort8*)&dst[base + 8] = o1;
}

// ---------------------------------------------------------------- GEMM (ring-pipelined)
template <int EPI>
__global__ __launch_bounds__(512) void gemm2_k(const unsigned short* __restrict__ A,
                                               const unsigned short* __restrict__ Bt,
                                               unsigned short* __restrict__ q_out,
                                               unsigned short* __restrict__ k_out,
                                               unsigned short* __restrict__ v_out,
                                               float* __restrict__ f_out) {
  __shared__ __align__(16) unsigned short smem[3 * 12288];

  const int tid = threadIdx.x;
  const int lane = tid & 63, wid = tid >> 6;
  const int wm = wid >> 2, wn = wid & 3;
  const int lr = lane & 15, lk = (lane >> 4) * 8;

  const int nwg = gridDim.x;
  const int cpx = nwg >> 3;
  const int swz = (blockIdx.x & 7) * cpx + (blockIdx.x >> 3);
  const int bx = swz & 63;
  const int by = swz >> 6;
  const int row0 = bx * 128, n00 = by * 256;

  const unsigned short* Aptr = A + (size_t)(row0 + (tid >> 2)) * 2048 + (tid & 3) * 8;
  const unsigned short* Bptr = Bt + (size_t)(n00 + (tid >> 2)) * 2048 + (tid & 3) * 8;

  f32x4 acc[4][4] = {};

#pragma unroll
  for (int p = 0; p < 2; p++) {
    unsigned short* s = &smem[p * 12288];
    GLDS16(Aptr + p * 32, &s[tid * 8]);
    GLDS16(Bptr + p * 32, &s[4096 + tid * 8]);
    GLDS16(Bptr + (size_t)128 * 2048 + p * 32, &s[8192 + tid * 8]);
  }

#pragma unroll 1
  for (int i = 0; i < 64; ++i) {
    if (i == 63) {
      asm volatile("s_waitcnt vmcnt(0)" ::: "memory");
    } else {
      asm volatile("s_waitcnt vmcnt(3)" ::: "memory");
    }
    asm volatile("s_barrier" ::: "memory");
    if (i + 2 < 64) {
      const int k0 = (i + 2) * 32;
      unsigned short* s = &smem[((i + 2) % 3) * 12288];
      GLDS16(Aptr + k0, &s[tid * 8]);
      GLDS16(Bptr + k0, &s[4096 + tid * 8]);
      GLDS16(Bptr + (size_t)128 * 2048 + k0, &s[8192 + tid * 8]);
    }

    const unsigned short* sA = &smem[(i % 3) * 12288];
    const unsigned short* sB = sA + 4096;
    bf16x8 af[4], bfr[4];
#pragma unroll
    for (int mi = 0; mi < 4; mi++)
      af[mi] = *(const bf16x8*)&sA[(wm * 64 + mi * 16 + lr) * 32 + lk];
#pragma unroll
    for (int ni = 0; ni < 4; ni++)
      bfr[ni] = *(const bf16x8*)&sB[(wn * 64 + ni * 16 + lr) * 32 + lk];

    __builtin_amdgcn_s_setprio(1);
#pragma unroll
    for (int mi = 0; mi < 4; mi++)
#pragma unroll
      for (int ni = 0; ni < 4; ni++)
        acc[mi][ni] =
            __builtin_amdgcn_mfma_f32_16x16x32_bf16(af[mi], bfr[ni], acc[mi][ni], 0, 0, 0);
    __builtin_amdgcn_s_setprio(0);
  }

  const int rbase = row0 + wm * 64;
  const int cbase = n00 + wn * 64;
#pragma unroll
  for (int mi = 0; mi < 4; mi++)
#pragma unroll
    for (int ni = 0; ni < 4; ni++)
#pragma unroll
      for (int r = 0; r < 4; r++) {
        int row = rbase + mi * 16 + (lane >> 4) * 4 + r;
        int col = cbase + ni * 16 + lr;
        float v = acc[mi][ni][r];
        if (EPI == 0) {
          if (col < 2048) {
            q_out[(size_t)row * 2048 + col] = f2bf(v);
          } else if (col < 2560) {
            k_out[(size_t)row * 512 + (col - 2048)] = f2bf(v);
          } else {
            int nv = col - 2560;
            int kvh = nv >> 7, d = nv & 127;
            int b = row >> 11, tt = row & 2047;
            v_out[((size_t)(b * NKVH + kvh) * HD + d) * T_SEQ + tt] = f2bf(v);
          }
        } else {
          f_out[(size_t)row * 2048 + col] = v;
        }
      }
}

// ---------------------------------------------------------------- RoPE tables + apply
__global__ __launch_bounds__(256) void rope_tab_k(float2* __restrict__ tab) {
  int idx = blockIdx.x * 256 + threadIdx.x;   // 2048*64 entries
  int t = idx >> 6, i = idx & 63;
  float theta = exp2f(-(float)i * (13.287712379549449f / 64.0f));
  float s, c;
  sincosf((float)t * theta, &s, &c);
  tab[idx] = make_float2(c, s);
}

__global__ __launch_bounds__(256) void rope_k(unsigned short* __restrict__ qb,
                                              unsigned short* __restrict__ kb,
                                              const float2* __restrict__ tab) {
  int idx = blockIdx.x * 256 + threadIdx.x;
  int i = idx & 63;
  int wi = idx >> 6;
  int hh = wi % (NH + NKVH);
  int bt = wi / (NH + NKVH);
  int t = bt & (T_SEQ - 1);
  unsigned short* p = (hh < NH) ? (qb + (size_t)bt * 2048 + hh * HD)
                                : (kb + (size_t)bt * 512 + (hh - NH) * HD);
  float2 cs = tab[(t << 6) + i];
  float x1 = bf2f(p[i]), x2 = bf2f(p[i + 64]);
  p[i] = f2bf(x1 * cs.x - x2 * cs.y);
  p[i + 64] = f2bf(x1 * cs.y + x2 * cs.x);
}

// ---------------------------------------------------------------- flash attention
// Structure as round 7/8 (3-slot ring, counted vmcnt, reverse-K, defer-rescale).
// VALU diet this round: hoisted per-row score constants cr[16] (tile-invariant),
// diag mask under wave-uniform branch, deferred-z softmax (pr = exp2(s1+z),
// z = slope2*k0 - m2), and HW v_cvt_pk_bf16_f32 for the P-pack.
__global__ __launch_bounds__(256) void attn_k(const unsigned short* __restrict__ qb,
                                              const unsigned short* __restrict__ kb,
                                              const unsigned short* __restrict__ vt,
                                              unsigned short* __restrict__ ao) {
  __shared__ __align__(16) unsigned short smem[24576];

  const int bid = blockIdx.x;
  const int j = 15 - (bid >> 6);                 // q-tile, heavy first
  const int g = (bid & 7) | (((bid >> 3) & 1) << 3);  // (b,kvh) group -> XCD bid&7
  const int hh = (bid >> 4) & 3;
  const int b = g >> 2, kvh = g & 3;
  const int h = kvh * 4 + hh;

  const int tid = threadIdx.x;
  const int wid = tid >> 6, lane = tid & 63;
  const int l31 = lane & 31, lh = lane >> 5;
  const int xr = l31 & 7;
  const float slope2 = exp2f(-0.5f * (float)(h + 1)) * LOG2E;
  const float scale2 = ATT_SCALE * LOG2E;

  const int q0 = j * 128 + wid * 32;
  const int dt_w = j * 4 + wid;
  const int nt = j * 4 + 4;

  const int krow = tid >> 4;
  const int cgk = (tid & 15) ^ (krow & 7);
  const int vr = tid >> 3;
  const int cgv = (tid & 7) ^ (vr & 7);

  const unsigned short* khead = kb + (size_t)(b * T_SEQ) * 512 + kvh * 128;
  const unsigned short* vhead = vt + (size_t)(b * NKVH + kvh) * HD * T_SEQ;

  auto stage = [&](int slot, int tile) {
    const int k0 = tile * 32;
    unsigned short* base = &smem[slot * 8192];
    GLDS16(khead + (size_t)(k0 + krow) * 512 + cgk * 8, base + tid * 8);
    GLDS16(khead + (size_t)(k0 + 16 + krow) * 512 + cgk * 8, base + 2048 + tid * 8);
    GLDS16(vhead + (size_t)(((cgv >> 2) << 6) + vr) * T_SEQ + k0 + (cgv & 3) * 8,
           base + 4096 + tid * 8);
    GLDS16(vhead + (size_t)(((cgv >> 2) << 6) + 32 + vr) * T_SEQ + k0 + (cgv & 3) * 8,
           base + 6144 + tid * 8);
  };

  unsigned short (*ot)[32][136] = (unsigned short(*)[32][136])smem;

  const unsigned short* qrow =
      qb + ((size_t)(b * T_SEQ + q0 + l31)) * 2048 + h * HD + lh * 8;
  bf16x8 qf[8];
#pragma unroll
  for (int ds = 0; ds < 8; ds++) qf[ds] = *(const bf16x8*)&qrow[ds * 16];

  f32x16 oacc[4] = {};
  float m2 = -1e30f, l_half = 0.f;
  const float arow = -slope2 * (float)(q0 + l31);

  // tile-invariant per-row score constants: cr[r] = slope2*crow + arow
  float cr[16];
#pragma unroll
  for (int r = 0; r < 16; r++) {
    const int crow = (r & 3) + 8 * (r >> 2) + 4 * lh;
    cr[r] = fmaf(slope2, (float)crow, arow);
  }

  stage(0, nt - 1);
  stage(1, nt - 2);

#pragma unroll 1
  for (int it = 0; it < nt; ++it) {
    const int tt = nt - 1 - it;
    if (it == nt - 1) {
      asm volatile("s_waitcnt vmcnt(0)" ::: "memory");
    } else {
      asm volatile("s_waitcnt vmcnt(4)" ::: "memory");
    }
    asm volatile("s_barrier" ::: "memory");
    if (tt >= 2) stage((it + 2) % 3, tt - 2);

    if (tt <= dt_w) {
      const int slot = it % 3;
      const unsigned short* Kb = &smem[slot * 8192];
      const unsigned short* Vb = &smem[slot * 8192 + 4096];
      const int k0 = tt * 32;

      bf16x8 kf[8];
#pragma unroll
      for (int ds = 0; ds < 8; ds++)
        kf[ds] = *(const bf16x8*)&Kb[l31 * 128 + ((2 * ds + lh) ^ xr) * 8];

      __builtin_amdgcn_s_setprio(1);
      f32x16 sc = 0.f;
#pragma unroll
      for (int ds = 0; ds < 8; ds++)
        sc = __builtin_amdgcn_mfma_f32_32x32x16_bf16(kf[ds], qf[ds], sc, 0, 0, 0);
      __builtin_amdgcn_s_setprio(0);

      bf16x8 vf[4][2];
#pragma unroll
      for (int dt = 0; dt < 4; dt++)
#pragma unroll
        for (int ks = 0; ks < 2; ks++)
          vf[dt][ks] = *(const bf16x8*)&Vb[((dt & 1) * 32 + l31) * 64 +
                                           (((dt >> 1) * 4 + 2 * ks + lh) ^ xr) * 8];

      // shifted scores: s1[r] = sc*scale2 + cr[r]; true score = s1 + slope2*k0
      float s1[16];
#pragma unroll
      for (int r = 0; r < 16; r++) s1[r] = fmaf(sc[r], scale2, cr[r]);
      if (tt == dt_w) {                          // wave-uniform: diag tile only
#pragma unroll
        for (int r = 0; r < 16; r++) {
          const int crow = (r & 3) + 8 * (r >> 2) + 4 * lh;
          if (crow > l31) s1[r] = -1e30f;
        }
      }

      // z folds the tile constant and running max into the exp argument
      float z = fmaf(slope2, (float)k0, -m2);

      // row max over shifted scores (15 fmax + 1 cross-half shuffle)
      float t8[8], t4[4];
#pragma unroll
      for (int i = 0; i < 8; i++) t8[i] = fmaxf(s1[i], s1[i + 8]);
#pragma unroll
      for (int i = 0; i < 4; i++) t4[i] = fmaxf(t8[i], t8[i + 4]);
      float mx = fmaxf(fmaxf(t4[0], t4[1]), fmaxf(t4[2], t4[3]));

      // speculative exp while the shuffle flies
      float pr[16];
#pragma unroll
      for (int r = 0; r < 16; r++) pr[r] = exp2f(s1[r] + z);

      mx = fmaxf(mx, __shfl_xor(mx, 32));
      if (__any(mx + z > 8.f)) {                 // rare with reverse-K streaming
        const float mt = (mx + z) + m2;          // true max
        const float mnew = fmaxf(m2, mt);
        const float corr = exp2f(m2 - mnew);
        l_half *= corr;
#pragma unroll
        for (int dt = 0; dt < 4; dt++) oacc[dt] *= corr;
        m2 = mnew;
        z = fmaf(slope2, (float)k0, -m2);
#pragma unroll
        for (int r = 0; r < 16; r++) pr[r] = exp2f(s1[r] + z);
      }

      // half-row sum (cross-half combine deferred to epilogue)
      float a8[8], a4[4];
#pragma unroll
      for (int i = 0; i < 8; i++) a8[i] = pr[i] + pr[i + 8];
#pragma unroll
      for (int i = 0; i < 4; i++) a4[i] = a8[i] + a8[i + 4];
      l_half += (a4[0] + a4[1]) + (a4[2] + a4[3]);

      // pack P via HW cvt_pk, redistribute to B-fragment layout
      unsigned int w[8];
#pragma unroll
      for (int i = 0; i < 8; i++) w[i] = cvtpk(pr[2 * i], pr[2 * i + 1]);
      const unsigned int ta = __shfl_xor(lh ? w[0] : w[2], 32);
      const unsigned int tb = __shfl_xor(lh ? w[1] : w[3], 32);
      const unsigned int tc = __shfl_xor(lh ? w[4] : w[6], 32);
      const unsigned int td = __shfl_xor(lh ? w[5] : w[7], 32);
      union U4 { unsigned int u[4]; bf16x8 v; } f0, f1;
      f0.u[0] = lh ? ta : w[0];
      f0.u[1] = lh ? tb : w[1];
      f0.u[2] = lh ? w[2] : ta;
      f0.u[3] = lh ? w[3] : tb;
      f1.u[0] = lh ? tc : w[4];
      f1.u[1] = lh ? td : w[5];
      f1.u[2] = lh ? w[6] : tc;
      f1.u[3] = lh ? w[7] : td;

      __builtin_amdgcn_s_setprio(1);
#pragma unroll
      for (int dt = 0; dt < 4; dt++) {
        oacc[dt] =
            __builtin_amdgcn_mfma_f32_32x32x16_bf16(vf[dt][0], f0.v, oacc[dt], 0, 0, 0);
        oacc[dt] =
            __builtin_amdgcn_mfma_f32_32x32x16_bf16(vf[dt][1], f1.v, oacc[dt], 0, 0, 0);
      }
      __builtin_amdgcn_s_setprio(0);
    }
  }

  const float l_tot = l_half + __shfl_xor(l_half, 32);
  const float inv = 1.0f / l_tot;
  __syncthreads();
#pragma unroll
  for (int dt = 0; dt < 4; dt++)
#pragma unroll
    for (int rg = 0; rg < 4; rg++) {
      ushort4v o;
#pragma unroll
      for (int jj = 0; jj < 4; jj++) o[jj] = f2bf(oacc[dt][rg * 4 + jj] * inv);
      *(ushort4v*)&ot[wid][l31][dt * 32 + rg * 8 + lh * 4] = o;
    }
  __syncthreads();
  const int rrow = lane >> 4, chunk = lane & 15;
#pragma unroll
  for (int ps = 0; ps < 8; ps++) {
    const int row = ps * 4 + rrow;
    ushort8 v = *(const ushort8*)&ot[wid][row][chunk * 8];
    *(ushort8*)&ao[((size_t)(b * T_SEQ + q0 + row)) * 2048 + h * HD + chunk * 8] = v;
  }
}

// ---------------------------------------------------------------- launch
extern "C" void kernel_launch(void* const* d_in, const int* in_sizes, int n_in,
                              void* d_out, int out_size, void* d_ws, size_t ws_size,
                              hipStream_t stream) {
  const float* x = (const float*)d_in[0];
  const float* Wq = (const float*)d_in[1];
  const float* Wk = (const float*)d_in[2];
  const float* Wv = (const float*)d_in[3];
  const float* Wo = (const float*)d_in[4];

  char* w = (char*)d_ws;
  unsigned short* xb = (unsigned short*)w;                       // 33.5MB; rope table + attn out reuse
  unsigned short* wqt = (unsigned short*)(w + 33554432);         // 12.6MB; reused for Wo^T
  unsigned short* qb = (unsigned short*)(w + 33554432 + 12582912);
  unsigned short* kb = (unsigned short*)(w + 33554432 + 12582912 + 33554432);
  unsigned short* vtb = (unsigned short*)(w + 33554432 + 12582912 + 33554432 + 8388608);
  float2* rtab = (float2*)w;  // 1MB, lives in xb region between gemm0 and attn

  castx_k<<<16384, 256, 0, stream>>>(x, xb);
  transw_k<<<dim3(32, 32), 256, 0, stream>>>(Wq, wqt, 2048);
  transw_k<<<dim3(8, 32), 256, 0, stream>>>(Wk, wqt + (size_t)2048 * 2048, 512);
  transw_k<<<dim3(8, 32), 256, 0, stream>>>(Wv, wqt + (size_t)2560 * 2048, 512);
  gemm2_k<0><<<768, 512, 0, stream>>>(xb, wqt, qb, kb, vtb, nullptr);
  rope_tab_k<<<512, 256, 0, stream>>>(rtab);
  rope_k<<<40960, 256, 0, stream>>>(qb, kb, rtab);
  transw_k<<<dim3(32, 32), 256, 0, stream>>>(Wo, wqt, 2048);
  attn_k<<<1024, 256, 0, stream>>>(qb, kb, vtb, xb);
  gemm2_k<1><<<512, 512, 0, stream>>>(xb, wqt, nullptr, nullptr, nullptr,
                                      (float*)d_out);
}